// Round 9
// baseline (183.015 us; speedup 1.0000x reference)
//
#include <hip/hip_runtime.h>

#define DD 256
#define TQ 512
#define TK 1024
#define C2 2.88539008177792681472f   // 2*log2(e)

__device__ __forceinline__ float fexp2(float x){ return __builtin_amdgcn_exp2f(x); }
__device__ __forceinline__ float frcp (float x){ return __builtin_amdgcn_rcpf(x); }

// -------- proj: out[r][c] = exp2( C2 * sum_d X[r][d] * W[c][d] ) --------
// tile 32 rows x 32 cols, 512 threads = 8 one-wave d-groups, 4x4 micro.  (R7, unchanged)
__global__ __launch_bounds__(512, 4) void proj_kernel(
    const float* __restrict__ query, const float* __restrict__ key,
    const float* __restrict__ Wq, const float* __restrict__ Wk,
    float* __restrict__ eqo, float* __restrict__ eko)
{
    __shared__ float smem[18432];
    float* Xs = smem;            // [256][36]: Xs[d*36 + r], r<32
    float* Ws = smem + 9216;     // [256][36]: Ws[d*36 + c], c<32

    int by = blockIdx.y;
    const float* X; const float* W; float* out;
    if (by < 16) { X = query; W = Wq; out = eqo; }
    else { by -= 16; X = key; W = Wk; out = eko; }
    const int r0 = by * 32, c0 = blockIdx.x * 32;
    const int tid = threadIdx.x;

    {
        int f = tid;
        #pragma unroll
        for (int rep = 0; rep < 4; ++rep, f += 512) {
            int row = f & 31, d4 = (f >> 5) << 2;
            float4 xv = *(const float4*)&X[(r0 + row) * DD + d4];
            Xs[(d4 + 0) * 36 + row] = xv.x;
            Xs[(d4 + 1) * 36 + row] = xv.y;
            Xs[(d4 + 2) * 36 + row] = xv.z;
            Xs[(d4 + 3) * 36 + row] = xv.w;
            float4 wv = *(const float4*)&W[(c0 + row) * DD + d4];
            Ws[(d4 + 0) * 36 + row] = wv.x;
            Ws[(d4 + 1) * 36 + row] = wv.y;
            Ws[(d4 + 2) * 36 + row] = wv.z;
            Ws[(d4 + 3) * 36 + row] = wv.w;
        }
    }
    __syncthreads();

    const int g = tid >> 6, t = tid & 63;    // 8 groups, each one full wave
    const int ry4 = (t >> 3) * 4, cx4 = (t & 7) * 4;
    float a[4][4] = {{0.f,0.f,0.f,0.f},{0.f,0.f,0.f,0.f},
                     {0.f,0.f,0.f,0.f},{0.f,0.f,0.f,0.f}};

    const int dbase = g * 32;
    #pragma unroll 4
    for (int d = dbase; d < dbase + 32; ++d) {
        float4 x4 = *(const float4*)&Xs[d * 36 + ry4];
        float4 w4 = *(const float4*)&Ws[d * 36 + cx4];
        float xx[4] = {x4.x, x4.y, x4.z, x4.w};
        float ww[4] = {w4.x, w4.y, w4.z, w4.w};
        #pragma unroll
        for (int i = 0; i < 4; ++i)
            #pragma unroll
            for (int j = 0; j < 4; ++j)
                a[i][j] = fmaf(xx[i], ww[j], a[i][j]);
    }

    __syncthreads();
    float* red = smem;
    if (g > 0) {
        int base = ((g - 1) * 64 + t) * 20;
        #pragma unroll
        for (int i = 0; i < 4; ++i)
            *(float4*)&red[base + i * 4] = make_float4(a[i][0], a[i][1], a[i][2], a[i][3]);
    }
    __syncthreads();
    if (g == 0) {
        #pragma unroll
        for (int p = 0; p < 7; ++p) {
            int base = (p * 64 + t) * 20;
            #pragma unroll
            for (int i = 0; i < 4; ++i) {
                float4 r4 = *(float4*)&red[base + i * 4];
                a[i][0] += r4.x; a[i][1] += r4.y; a[i][2] += r4.z; a[i][3] += r4.w;
            }
        }
        #pragma unroll
        for (int i = 0; i < 4; ++i) {
            float4 s = make_float4(fexp2(C2 * a[i][0]), fexp2(C2 * a[i][1]),
                                   fexp2(C2 * a[i][2]), fexp2(C2 * a[i][3]));
            *(float4*)&out[(r0 + ry4 + i) * DD + c0 + cx4] = s;
        }
    }
}

// -------- scores: out[q][k] = vsum - 2 * sum_d v[d] / (Eq[q][d]*Ek[k][d] + 1) --------
// tile 32 q x 32 k, 512 threads = 8 one-wave d-groups, 4x4 micro, quad common denom.
// R9: software-pipelined main loop — prefetch d-quad s+1 into registers before
// computing d-quad s (hides ds_read latency; ~108 VGPR, fits 128 cap at (512,4)).
__global__ __launch_bounds__(512, 4) void scores_kernel(
    const float* __restrict__ eqg, const float* __restrict__ ekg,
    const float* __restrict__ v, float* __restrict__ out)
{
    __shared__ float smem[18690];
    float* eq = smem;            // [256][36]: eq[d*36 + r], r<32
    float* ek = smem + 9216;     // [256][36]: ek[d*36 + c], c<32
    float* vs = smem + 18432;    // [256]

    const int qb = blockIdx.y, kb = blockIdx.x;
    const int tid = threadIdx.x;

    {
        int f = tid;
        #pragma unroll
        for (int rep = 0; rep < 4; ++rep, f += 512) {
            int row = f & 31, d4 = (f >> 5) << 2;
            float4 qv = *(const float4*)&eqg[(qb * 32 + row) * DD + d4];
            eq[(d4 + 0) * 36 + row] = qv.x;
            eq[(d4 + 1) * 36 + row] = qv.y;
            eq[(d4 + 2) * 36 + row] = qv.z;
            eq[(d4 + 3) * 36 + row] = qv.w;
            float4 kv = *(const float4*)&ekg[(kb * 32 + row) * DD + d4];
            ek[(d4 + 0) * 36 + row] = kv.x;
            ek[(d4 + 1) * 36 + row] = kv.y;
            ek[(d4 + 2) * 36 + row] = kv.z;
            ek[(d4 + 3) * 36 + row] = kv.w;
        }
        if (tid < 64) {
            float4 vv = *(const float4*)&v[tid * 4];
            *(float4*)&vs[tid * 4] = vv;
            float s = vv.x + vv.y + vv.z + vv.w;
            #pragma unroll
            for (int m = 1; m < 64; m <<= 1) s += __shfl_xor(s, m);
            if (tid == 0) smem[18688] = s;
        }
    }
    __syncthreads();

    const int g = tid >> 6, t = tid & 63;    // 8 groups, each one full wave
    const int qp4 = (t >> 3) * 4, kq4 = (t & 7) * 4;
    float a[4][4] = {{0.f,0.f,0.f,0.f},{0.f,0.f,0.f,0.f},
                     {0.f,0.f,0.f,0.f},{0.f,0.f,0.f,0.f}};

    const int dbase = g * 32;

    // prefetch s = 0
    float4 v4c, Qc[4], Kc[4];
    v4c = *(const float4*)&vs[dbase];
    #pragma unroll
    for (int di = 0; di < 4; ++di) {
        Qc[di] = *(const float4*)&eq[(dbase + di) * 36 + qp4];
        Kc[di] = *(const float4*)&ek[(dbase + di) * 36 + kq4];
    }

    #pragma unroll
    for (int s = 0; s < 8; ++s) {
        float4 v4n, Qn[4], Kn[4];
        if (s < 7) {
            const int d1 = dbase + (s + 1) * 4;
            v4n = *(const float4*)&vs[d1];
            #pragma unroll
            for (int di = 0; di < 4; ++di) {
                Qn[di] = *(const float4*)&eq[(d1 + di) * 36 + qp4];
                Kn[di] = *(const float4*)&ek[(d1 + di) * 36 + kq4];
            }
        }

        float Qr[4][4], Kr[4][4];
        #pragma unroll
        for (int di = 0; di < 4; ++di) {
            Qr[di][0] = Qc[di].x; Qr[di][1] = Qc[di].y; Qr[di][2] = Qc[di].z; Qr[di][3] = Qc[di].w;
            Kr[di][0] = Kc[di].x; Kr[di][1] = Kc[di].y; Kr[di][2] = Kc[di].z; Kr[di][3] = Kc[di].w;
        }
        #pragma unroll
        for (int i = 0; i < 4; ++i) {
            #pragma unroll
            for (int j = 0; j < 4; ++j) {
                float t0 = fmaf(Qr[0][i], Kr[0][j], 1.f);
                float t1 = fmaf(Qr[1][i], Kr[1][j], 1.f);
                float t2 = fmaf(Qr[2][i], Kr[2][j], 1.f);
                float t3 = fmaf(Qr[3][i], Kr[3][j], 1.f);
                float A  = t0 * t1;
                float B  = t2 * t3;
                float den = A * B;
                float n01 = fmaf(v4c.x, t1, v4c.y * t0);
                float n23 = fmaf(v4c.z, t3, v4c.w * t2);
                float num = fmaf(n01, B, n23 * A);
                a[i][j] = fmaf(num, frcp(den), a[i][j]);
            }
        }

        if (s < 7) {
            v4c = v4n;
            #pragma unroll
            for (int di = 0; di < 4; ++di) { Qc[di] = Qn[di]; Kc[di] = Kn[di]; }
        }
    }

    __syncthreads();   // all reads of eq/ek done; safe to alias as reduction buf
    float* red = smem;
    if (g > 0) {
        int base = ((g - 1) * 64 + t) * 20;   // 16B-aligned, 2-way banks (free)
        #pragma unroll
        for (int i = 0; i < 4; ++i)
            *(float4*)&red[base + i * 4] = make_float4(a[i][0], a[i][1], a[i][2], a[i][3]);
    }
    __syncthreads();
    if (g == 0) {
        #pragma unroll
        for (int p = 0; p < 7; ++p) {
            int base = (p * 64 + t) * 20;
            #pragma unroll
            for (int i = 0; i < 4; ++i) {
                float4 r4 = *(float4*)&red[base + i * 4];
                a[i][0] += r4.x; a[i][1] += r4.y; a[i][2] += r4.z; a[i][3] += r4.w;
            }
        }
        float vsum = smem[18688];
        const int row0 = qb * 32 + qp4, col = kb * 32 + kq4;
        #pragma unroll
        for (int i = 0; i < 4; ++i) {
            float4 s = make_float4(fmaf(-2.f, a[i][0], vsum), fmaf(-2.f, a[i][1], vsum),
                                   fmaf(-2.f, a[i][2], vsum), fmaf(-2.f, a[i][3], vsum));
            *(float4*)&out[(row0 + i) * TK + col] = s;
        }
    }
}

extern "C" void kernel_launch(void* const* d_in, const int* in_sizes, int n_in,
                              void* d_out, int out_size, void* d_ws, size_t ws_size,
                              hipStream_t stream) {
    const float* query = (const float*)d_in[0];   // [512,256]
    const float* key   = (const float*)d_in[1];   // [1024,256]
    // d_in[2] = value, unused by the reference
    const float* Wq    = (const float*)d_in[3];   // [256,256]
    const float* Wk    = (const float*)d_in[4];   // [256,256]
    const float* vw    = (const float*)d_in[5];   // [1,256]
    float* out = (float*)d_out;                   // [512,1024]

    float* eq = (float*)d_ws;                     // 512*256 f32
    float* ek = eq + TQ * DD;                     // 1024*256 f32

    proj_kernel<<<dim3(8, 48), 512, 0, stream>>>(query, key, Wq, Wk, eq, ek);
    scores_kernel<<<dim3(TK / 32, TQ / 32), 512, 0, stream>>>(eq, ek, vw, out);
}

// Round 10
// 30.712 us; speedup vs baseline: 5.9591x; 5.9591x over previous
//
#include <hip/hip_runtime.h>

#define DD 256
#define TQ 512
#define TK 1024
#define C2 2.88539008177792681472f   // 2*log2(e)

__device__ __forceinline__ float fexp2(float x){ return __builtin_amdgcn_exp2f(x); }
__device__ __forceinline__ float frcp (float x){ return __builtin_amdgcn_rcpf(x); }

// -------- proj: out[r][c] = exp2( C2 * sum_d X[r][d] * W[c][d] ) --------
// tile 32 rows x 32 cols, 512 threads = 8 one-wave d-groups, 4x4 micro.  (R7, unchanged)
__global__ __launch_bounds__(512, 4) void proj_kernel(
    const float* __restrict__ query, const float* __restrict__ key,
    const float* __restrict__ Wq, const float* __restrict__ Wk,
    float* __restrict__ eqo, float* __restrict__ eko)
{
    __shared__ float smem[18432];
    float* Xs = smem;            // [256][36]: Xs[d*36 + r], r<32
    float* Ws = smem + 9216;     // [256][36]: Ws[d*36 + c], c<32

    int by = blockIdx.y;
    const float* X; const float* W; float* out;
    if (by < 16) { X = query; W = Wq; out = eqo; }
    else { by -= 16; X = key; W = Wk; out = eko; }
    const int r0 = by * 32, c0 = blockIdx.x * 32;
    const int tid = threadIdx.x;

    {
        int f = tid;
        #pragma unroll
        for (int rep = 0; rep < 4; ++rep, f += 512) {
            int row = f & 31, d4 = (f >> 5) << 2;
            float4 xv = *(const float4*)&X[(r0 + row) * DD + d4];
            Xs[(d4 + 0) * 36 + row] = xv.x;
            Xs[(d4 + 1) * 36 + row] = xv.y;
            Xs[(d4 + 2) * 36 + row] = xv.z;
            Xs[(d4 + 3) * 36 + row] = xv.w;
            float4 wv = *(const float4*)&W[(c0 + row) * DD + d4];
            Ws[(d4 + 0) * 36 + row] = wv.x;
            Ws[(d4 + 1) * 36 + row] = wv.y;
            Ws[(d4 + 2) * 36 + row] = wv.z;
            Ws[(d4 + 3) * 36 + row] = wv.w;
        }
    }
    __syncthreads();

    const int g = tid >> 6, t = tid & 63;    // 8 groups, each one full wave
    const int ry4 = (t >> 3) * 4, cx4 = (t & 7) * 4;
    float a[4][4] = {{0.f,0.f,0.f,0.f},{0.f,0.f,0.f,0.f},
                     {0.f,0.f,0.f,0.f},{0.f,0.f,0.f,0.f}};

    const int dbase = g * 32;
    #pragma unroll 4
    for (int d = dbase; d < dbase + 32; ++d) {
        float4 x4 = *(const float4*)&Xs[d * 36 + ry4];
        float4 w4 = *(const float4*)&Ws[d * 36 + cx4];
        float xx[4] = {x4.x, x4.y, x4.z, x4.w};
        float ww[4] = {w4.x, w4.y, w4.z, w4.w};
        #pragma unroll
        for (int i = 0; i < 4; ++i)
            #pragma unroll
            for (int j = 0; j < 4; ++j)
                a[i][j] = fmaf(xx[i], ww[j], a[i][j]);
    }

    __syncthreads();
    float* red = smem;
    if (g > 0) {
        int base = ((g - 1) * 64 + t) * 20;
        #pragma unroll
        for (int i = 0; i < 4; ++i)
            *(float4*)&red[base + i * 4] = make_float4(a[i][0], a[i][1], a[i][2], a[i][3]);
    }
    __syncthreads();
    if (g == 0) {
        #pragma unroll
        for (int p = 0; p < 7; ++p) {
            int base = (p * 64 + t) * 20;
            #pragma unroll
            for (int i = 0; i < 4; ++i) {
                float4 r4 = *(float4*)&red[base + i * 4];
                a[i][0] += r4.x; a[i][1] += r4.y; a[i][2] += r4.z; a[i][3] += r4.w;
            }
        }
        #pragma unroll
        for (int i = 0; i < 4; ++i) {
            float4 s = make_float4(fexp2(C2 * a[i][0]), fexp2(C2 * a[i][1]),
                                   fexp2(C2 * a[i][2]), fexp2(C2 * a[i][3]));
            *(float4*)&out[(r0 + ry4 + i) * DD + c0 + cx4] = s;
        }
    }
}

// -------- scores: out[q][k] = vsum - 2 * sum_d v[d] / (Eq[q][d]*Ek[k][d] + 1) --------
// tile 32 q x 32 k, 512 threads = 8 one-wave d-groups, 4x4 micro, quad common denom.
// Software-pipelined main loop (prefetch d-quad s+1 before computing s).
// __launch_bounds__(512, 2): VGPR cap >=128 so the ~100-reg pipeline fits WITHOUT
// spilling (R9's (512,4) capped at 64 VGPR -> 312MB scratch traffic, 183us).
__global__ __launch_bounds__(512, 2) void scores_kernel(
    const float* __restrict__ eqg, const float* __restrict__ ekg,
    const float* __restrict__ v, float* __restrict__ out)
{
    __shared__ float smem[18690];
    float* eq = smem;            // [256][36]: eq[d*36 + r], r<32
    float* ek = smem + 9216;     // [256][36]: ek[d*36 + c], c<32
    float* vs = smem + 18432;    // [256]

    const int qb = blockIdx.y, kb = blockIdx.x;
    const int tid = threadIdx.x;

    {
        int f = tid;
        #pragma unroll
        for (int rep = 0; rep < 4; ++rep, f += 512) {
            int row = f & 31, d4 = (f >> 5) << 2;
            float4 qv = *(const float4*)&eqg[(qb * 32 + row) * DD + d4];
            eq[(d4 + 0) * 36 + row] = qv.x;
            eq[(d4 + 1) * 36 + row] = qv.y;
            eq[(d4 + 2) * 36 + row] = qv.z;
            eq[(d4 + 3) * 36 + row] = qv.w;
            float4 kv = *(const float4*)&ekg[(kb * 32 + row) * DD + d4];
            ek[(d4 + 0) * 36 + row] = kv.x;
            ek[(d4 + 1) * 36 + row] = kv.y;
            ek[(d4 + 2) * 36 + row] = kv.z;
            ek[(d4 + 3) * 36 + row] = kv.w;
        }
        if (tid < 64) {
            float4 vv = *(const float4*)&v[tid * 4];
            *(float4*)&vs[tid * 4] = vv;
            float s = vv.x + vv.y + vv.z + vv.w;
            #pragma unroll
            for (int m = 1; m < 64; m <<= 1) s += __shfl_xor(s, m);
            if (tid == 0) smem[18688] = s;
        }
    }
    __syncthreads();

    const int g = tid >> 6, t = tid & 63;    // 8 groups, each one full wave
    const int qp4 = (t >> 3) * 4, kq4 = (t & 7) * 4;
    float a[4][4] = {{0.f,0.f,0.f,0.f},{0.f,0.f,0.f,0.f},
                     {0.f,0.f,0.f,0.f},{0.f,0.f,0.f,0.f}};

    const int dbase = g * 32;

    // prefetch s = 0
    float4 v4c, Qc[4], Kc[4];
    v4c = *(const float4*)&vs[dbase];
    #pragma unroll
    for (int di = 0; di < 4; ++di) {
        Qc[di] = *(const float4*)&eq[(dbase + di) * 36 + qp4];
        Kc[di] = *(const float4*)&ek[(dbase + di) * 36 + kq4];
    }

    #pragma unroll
    for (int s = 0; s < 8; ++s) {
        float4 v4n, Qn[4], Kn[4];
        if (s < 7) {
            const int d1 = dbase + (s + 1) * 4;
            v4n = *(const float4*)&vs[d1];
            #pragma unroll
            for (int di = 0; di < 4; ++di) {
                Qn[di] = *(const float4*)&eq[(d1 + di) * 36 + qp4];
                Kn[di] = *(const float4*)&ek[(d1 + di) * 36 + kq4];
            }
        }

        float Qr[4][4], Kr[4][4];
        #pragma unroll
        for (int di = 0; di < 4; ++di) {
            Qr[di][0] = Qc[di].x; Qr[di][1] = Qc[di].y; Qr[di][2] = Qc[di].z; Qr[di][3] = Qc[di].w;
            Kr[di][0] = Kc[di].x; Kr[di][1] = Kc[di].y; Kr[di][2] = Kc[di].z; Kr[di][3] = Kc[di].w;
        }
        #pragma unroll
        for (int i = 0; i < 4; ++i) {
            #pragma unroll
            for (int j = 0; j < 4; ++j) {
                float t0 = fmaf(Qr[0][i], Kr[0][j], 1.f);
                float t1 = fmaf(Qr[1][i], Kr[1][j], 1.f);
                float t2 = fmaf(Qr[2][i], Kr[2][j], 1.f);
                float t3 = fmaf(Qr[3][i], Kr[3][j], 1.f);
                float A  = t0 * t1;
                float B  = t2 * t3;
                float den = A * B;
                float n01 = fmaf(v4c.x, t1, v4c.y * t0);
                float n23 = fmaf(v4c.z, t3, v4c.w * t2);
                float num = fmaf(n01, B, n23 * A);
                a[i][j] = fmaf(num, frcp(den), a[i][j]);
            }
        }

        if (s < 7) {
            v4c = v4n;
            #pragma unroll
            for (int di = 0; di < 4; ++di) { Qc[di] = Qn[di]; Kc[di] = Kn[di]; }
        }
    }

    __syncthreads();   // all reads of eq/ek done; safe to alias as reduction buf
    float* red = smem;
    if (g > 0) {
        int base = ((g - 1) * 64 + t) * 20;   // 16B-aligned, 2-way banks (free)
        #pragma unroll
        for (int i = 0; i < 4; ++i)
            *(float4*)&red[base + i * 4] = make_float4(a[i][0], a[i][1], a[i][2], a[i][3]);
    }
    __syncthreads();
    if (g == 0) {
        #pragma unroll
        for (int p = 0; p < 7; ++p) {
            int base = (p * 64 + t) * 20;
            #pragma unroll
            for (int i = 0; i < 4; ++i) {
                float4 r4 = *(float4*)&red[base + i * 4];
                a[i][0] += r4.x; a[i][1] += r4.y; a[i][2] += r4.z; a[i][3] += r4.w;
            }
        }
        float vsum = smem[18688];
        const int row0 = qb * 32 + qp4, col = kb * 32 + kq4;
        #pragma unroll
        for (int i = 0; i < 4; ++i) {
            float4 s = make_float4(fmaf(-2.f, a[i][0], vsum), fmaf(-2.f, a[i][1], vsum),
                                   fmaf(-2.f, a[i][2], vsum), fmaf(-2.f, a[i][3], vsum));
            *(float4*)&out[(row0 + i) * TK + col] = s;
        }
    }
}

extern "C" void kernel_launch(void* const* d_in, const int* in_sizes, int n_in,
                              void* d_out, int out_size, void* d_ws, size_t ws_size,
                              hipStream_t stream) {
    const float* query = (const float*)d_in[0];   // [512,256]
    const float* key   = (const float*)d_in[1];   // [1024,256]
    // d_in[2] = value, unused by the reference
    const float* Wq    = (const float*)d_in[3];   // [256,256]
    const float* Wk    = (const float*)d_in[4];   // [256,256]
    const float* vw    = (const float*)d_in[5];   // [1,256]
    float* out = (float*)d_out;                   // [512,1024]

    float* eq = (float*)d_ws;                     // 512*256 f32
    float* ek = eq + TQ * DD;                     // 1024*256 f32

    proj_kernel<<<dim3(8, 48), 512, 0, stream>>>(query, key, Wq, Wk, eq, ek);
    scores_kernel<<<dim3(TK / 32, TQ / 32), 512, 0, stream>>>(eq, ek, vw, out);
}

// Round 11
// 29.866 us; speedup vs baseline: 6.1279x; 1.0283x over previous
//
#include <hip/hip_runtime.h>

#define DD 256
#define TQ 512
#define TK 1024
#define C2 2.88539008177792681472f   // 2*log2(e)

__device__ __forceinline__ float fexp2(float x){ return __builtin_amdgcn_exp2f(x); }
__device__ __forceinline__ float frcp (float x){ return __builtin_amdgcn_rcpf(x); }

typedef short bf16x8 __attribute__((ext_vector_type(8)));
typedef float f32x4  __attribute__((ext_vector_type(4)));

__device__ __forceinline__ short rne_bf16(float x){
    union { float f; unsigned u; } v; v.f = x;
    unsigned r = v.u + 0x7FFFu + ((v.u >> 16) & 1u);
    return (short)(r >> 16);
}

// -------- proj via MFMA: out[r][c] = exp2( C2 * sum_d X[r][d] * W[c][d] ) --------
// One 16x16 output tile per wave, K=256 via 8 x mfma_f32_16x16x32_bf16.
// A-frag: lane l holds X[rt*16 + (l&15)][k0 + (l>>4)*8 + j], j=0..7 (contiguous d).
// B-frag: lane l holds W[ct*16 + (l&15)][k0 + (l>>4)*8 + j]   (B[k][n] = W[n][k]).
// C/D:    lane l, reg r -> row rt*16 + (l>>4)*4 + r, col ct*16 + (l&15)  [m89].
// qt: 32x16 tiles (512 waves), kt: 64x16 tiles (1024 waves); 4 waves/block.
__global__ __launch_bounds__(256) void proj_mfma_kernel(
    const float* __restrict__ query, const float* __restrict__ key,
    const float* __restrict__ Wq, const float* __restrict__ Wk,
    float* __restrict__ eqo, float* __restrict__ eko)
{
    const int w = threadIdx.x >> 6, l = threadIdx.x & 63;
    int i = blockIdx.x * 4 + w;
    const float* X; const float* W; float* out;
    if (i < 512) { X = query; W = Wq; out = eqo; }
    else { i -= 512; X = key; W = Wk; out = eko; }
    const int rt = i >> 4, ct = i & 15;
    const int lr = l & 15, kg = (l >> 4) * 8;
    const float* Xp = X + (rt * 16 + lr) * DD + kg;
    const float* Wp = W + (ct * 16 + lr) * DD + kg;

    f32x4 acc = {0.f, 0.f, 0.f, 0.f};
    #pragma unroll
    for (int k0 = 0; k0 < DD; k0 += 32) {
        float4 xa = *(const float4*)&Xp[k0];
        float4 xb = *(const float4*)&Xp[k0 + 4];
        float4 wa = *(const float4*)&Wp[k0];
        float4 wb = *(const float4*)&Wp[k0 + 4];
        bf16x8 af, bf;
        af[0] = rne_bf16(xa.x); af[1] = rne_bf16(xa.y);
        af[2] = rne_bf16(xa.z); af[3] = rne_bf16(xa.w);
        af[4] = rne_bf16(xb.x); af[5] = rne_bf16(xb.y);
        af[6] = rne_bf16(xb.z); af[7] = rne_bf16(xb.w);
        bf[0] = rne_bf16(wa.x); bf[1] = rne_bf16(wa.y);
        bf[2] = rne_bf16(wa.z); bf[3] = rne_bf16(wa.w);
        bf[4] = rne_bf16(wb.x); bf[5] = rne_bf16(wb.y);
        bf[6] = rne_bf16(wb.z); bf[7] = rne_bf16(wb.w);
        acc = __builtin_amdgcn_mfma_f32_16x16x32_bf16(af, bf, acc, 0, 0, 0);
    }

    const int orow = rt * 16 + (l >> 4) * 4;
    const int ocol = ct * 16 + lr;
    #pragma unroll
    for (int r = 0; r < 4; ++r)
        out[(orow + r) * DD + ocol] = fexp2(C2 * acc[r]);
}

// -------- scores: out[q][k] = vsum - 2 * sum_d v[d] / (Eq[q][d]*Ek[k][d] + 1) --------
// tile 32 q x 32 k, 512 threads = 8 one-wave d-groups, 4x4 micro, quad common denom.
// d-major LDS stride 36 (conflict-free b128 reads).  (exact R7 copy — best so far)
__global__ __launch_bounds__(512, 4) void scores_kernel(
    const float* __restrict__ eqg, const float* __restrict__ ekg,
    const float* __restrict__ v, float* __restrict__ out)
{
    __shared__ float smem[18690];
    float* eq = smem;            // [256][36]: eq[d*36 + r], r<32
    float* ek = smem + 9216;     // [256][36]: ek[d*36 + c], c<32
    float* vs = smem + 18432;    // [256]

    const int qb = blockIdx.y, kb = blockIdx.x;
    const int tid = threadIdx.x;

    {
        int f = tid;
        #pragma unroll
        for (int rep = 0; rep < 4; ++rep, f += 512) {
            int row = f & 31, d4 = (f >> 5) << 2;
            float4 qv = *(const float4*)&eqg[(qb * 32 + row) * DD + d4];
            eq[(d4 + 0) * 36 + row] = qv.x;
            eq[(d4 + 1) * 36 + row] = qv.y;
            eq[(d4 + 2) * 36 + row] = qv.z;
            eq[(d4 + 3) * 36 + row] = qv.w;
            float4 kv = *(const float4*)&ekg[(kb * 32 + row) * DD + d4];
            ek[(d4 + 0) * 36 + row] = kv.x;
            ek[(d4 + 1) * 36 + row] = kv.y;
            ek[(d4 + 2) * 36 + row] = kv.z;
            ek[(d4 + 3) * 36 + row] = kv.w;
        }
        if (tid < 64) {
            float4 vv = *(const float4*)&v[tid * 4];
            *(float4*)&vs[tid * 4] = vv;
            float s = vv.x + vv.y + vv.z + vv.w;
            #pragma unroll
            for (int m = 1; m < 64; m <<= 1) s += __shfl_xor(s, m);
            if (tid == 0) smem[18688] = s;
        }
    }
    __syncthreads();

    const int g = tid >> 6, t = tid & 63;    // 8 groups, each one full wave
    const int qp4 = (t >> 3) * 4, kq4 = (t & 7) * 4;
    float a[4][4] = {{0.f,0.f,0.f,0.f},{0.f,0.f,0.f,0.f},
                     {0.f,0.f,0.f,0.f},{0.f,0.f,0.f,0.f}};

    const int dbase = g * 32;
    #pragma unroll 2
    for (int s = 0; s < 8; ++s) {
        const int d0 = dbase + s * 4;
        float4 v4 = *(const float4*)&vs[d0];
        float Qr[4][4], Kr[4][4];             // [di][q/k idx], all-constant indexing
        #pragma unroll
        for (int di = 0; di < 4; ++di) {
            float4 q4 = *(const float4*)&eq[(d0 + di) * 36 + qp4];
            Qr[di][0] = q4.x; Qr[di][1] = q4.y; Qr[di][2] = q4.z; Qr[di][3] = q4.w;
            float4 k4 = *(const float4*)&ek[(d0 + di) * 36 + kq4];
            Kr[di][0] = k4.x; Kr[di][1] = k4.y; Kr[di][2] = k4.z; Kr[di][3] = k4.w;
        }
        #pragma unroll
        for (int i = 0; i < 4; ++i) {
            #pragma unroll
            for (int j = 0; j < 4; ++j) {
                float t0 = fmaf(Qr[0][i], Kr[0][j], 1.f);
                float t1 = fmaf(Qr[1][i], Kr[1][j], 1.f);
                float t2 = fmaf(Qr[2][i], Kr[2][j], 1.f);
                float t3 = fmaf(Qr[3][i], Kr[3][j], 1.f);
                float A  = t0 * t1;
                float B  = t2 * t3;
                float den = A * B;
                float n01 = fmaf(v4.x, t1, v4.y * t0);
                float n23 = fmaf(v4.z, t3, v4.w * t2);
                float num = fmaf(n01, B, n23 * A);
                a[i][j] = fmaf(num, frcp(den), a[i][j]);
            }
        }
    }

    __syncthreads();   // all reads of eq/ek done; safe to alias as reduction buf
    float* red = smem;
    if (g > 0) {
        int base = ((g - 1) * 64 + t) * 20;   // 16B-aligned, 2-way banks (free)
        #pragma unroll
        for (int i = 0; i < 4; ++i)
            *(float4*)&red[base + i * 4] = make_float4(a[i][0], a[i][1], a[i][2], a[i][3]);
    }
    __syncthreads();
    if (g == 0) {
        #pragma unroll
        for (int p = 0; p < 7; ++p) {
            int base = (p * 64 + t) * 20;
            #pragma unroll
            for (int i = 0; i < 4; ++i) {
                float4 r4 = *(float4*)&red[base + i * 4];
                a[i][0] += r4.x; a[i][1] += r4.y; a[i][2] += r4.z; a[i][3] += r4.w;
            }
        }
        float vsum = smem[18688];
        const int row0 = qb * 32 + qp4, col = kb * 32 + kq4;
        #pragma unroll
        for (int i = 0; i < 4; ++i) {
            float4 s = make_float4(fmaf(-2.f, a[i][0], vsum), fmaf(-2.f, a[i][1], vsum),
                                   fmaf(-2.f, a[i][2], vsum), fmaf(-2.f, a[i][3], vsum));
            *(float4*)&out[(row0 + i) * TK + col] = s;
        }
    }
}

extern "C" void kernel_launch(void* const* d_in, const int* in_sizes, int n_in,
                              void* d_out, int out_size, void* d_ws, size_t ws_size,
                              hipStream_t stream) {
    const float* query = (const float*)d_in[0];   // [512,256]
    const float* key   = (const float*)d_in[1];   // [1024,256]
    // d_in[2] = value, unused by the reference
    const float* Wq    = (const float*)d_in[3];   // [256,256]
    const float* Wk    = (const float*)d_in[4];   // [256,256]
    const float* vw    = (const float*)d_in[5];   // [1,256]
    float* out = (float*)d_out;                   // [512,1024]

    float* eq = (float*)d_ws;                     // 512*256 f32
    float* ek = eq + TQ * DD;                     // 1024*256 f32

    proj_mfma_kernel<<<384, 256, 0, stream>>>(query, key, Wq, Wk, eq, ek);
    scores_kernel<<<dim3(TK / 32, TQ / 32), 512, 0, stream>>>(eq, ek, vw, out);
}